// Round 1
// 806.516 us; speedup vs baseline: 1.0064x; 1.0064x over previous
//
#include <hip/hip_runtime.h>
#include <stdint.h>

#define N_NODES 100000
#define N_PAD   100032            // 1563 * 64, padded rows for MFMA GEMM
#define N_EDGES 1600000
#define DIM 128
#define NLAYERS 4
#define NGRAPH 128
#define NCLS 10
#define EPSV 1e-5f

#define BIN_SHIFT 9
#define NBUCKET ((N_NODES + 511) >> 9)              // 196
#define P1_EPB 4096
#define P1_BLOCKS ((N_EDGES + P1_EPB - 1) / P1_EPB) // 391

typedef __attribute__((ext_vector_type(8))) short short8_t;   // 8 bf16
typedef __attribute__((ext_vector_type(4))) float float4_t;   // 4 fp32 acc

// ---------------- bf16 helpers ----------------

__device__ __forceinline__ float bf_lo(uint32_t u) { return __uint_as_float(u << 16); }
__device__ __forceinline__ float bf_hi(uint32_t u) { return __uint_as_float(u & 0xffff0000u); }
__device__ __forceinline__ uint32_t f2bf_rne(float f) {
    uint32_t x = __float_as_uint(f);
    return (x + 0x7fffu + ((x >> 16) & 1u)) >> 16;
}
__device__ __forceinline__ uint32_t pack_bf2(float a, float b) {
    return f2bf_rne(a) | (f2bf_rne(b) << 16);
}
__device__ __forceinline__ float4 unpack4(uint2 u) {
    return make_float4(bf_lo(u.x), bf_hi(u.x), bf_lo(u.y), bf_hi(u.y));
}

// ---------------- prepass kernels ----------------

// graph boundaries from SORTED batch (no atomics); also zero bucket counters
__global__ void k_node_meta(const int* __restrict__ batch, int* __restrict__ gstart,
                            int* __restrict__ bcnt) {
    int i = blockIdx.x * blockDim.x + threadIdx.x;
    if (i < NBUCKET) bcnt[i] = 0;
    if (i >= N_NODES) return;
    int b = batch[i];
    if (i == 0) {
        for (int g = 0; g <= b; g++) gstart[g] = 0;
    } else {
        int bp = batch[i - 1];
        for (int g = bp + 1; g <= b; g++) gstart[g] = i;
    }
    if (i == N_NODES - 1) {
        for (int g = b + 1; g <= NGRAPH; g++) gstart[g] = N_NODES;
    }
}

// histogram edges by dst bucket
__global__ __launch_bounds__(256) void k_bhist(const int* __restrict__ ei, int* __restrict__ bcnt) {
    __shared__ int hist[NBUCKET];
    int t = threadIdx.x;
    for (int i = t; i < NBUCKET; i += 256) hist[i] = 0;
    __syncthreads();
    int e0 = blockIdx.x * P1_EPB;
    int e1 = e0 + P1_EPB; if (e1 > N_EDGES) e1 = N_EDGES;
    for (int e = e0 + t; e < e1; e += 256) atomicAdd(&hist[ei[N_EDGES + e] >> BIN_SHIFT], 1);
    __syncthreads();
    for (int i = t; i < NBUCKET; i += 256) if (hist[i]) atomicAdd(&bcnt[i], hist[i]);
}

// exclusive scan of bucket counts -> bucket_off[0..NBUCKET]; init bcur
__global__ __launch_bounds__(256) void k_bscan(const int* __restrict__ bcnt,
                                               int* __restrict__ bucket_off, int* __restrict__ bcur) {
    __shared__ int s[256];
    int t = threadIdx.x;
    int v = (t < NBUCKET) ? bcnt[t] : 0;
    s[t] = v; __syncthreads();
    for (int off = 1; off < 256; off <<= 1) {
        int a = (t >= off) ? s[t - off] : 0;
        __syncthreads();
        s[t] += a;
        __syncthreads();
    }
    if (t < NBUCKET) { bucket_off[t] = s[t] - v; bcur[t] = s[t] - v; }
    if (t == 0) bucket_off[NBUCKET] = s[255];
}

// pass 1: bin edges by dst bucket (append-sequential writes per bucket)
__global__ __launch_bounds__(256) void k_bin_edges(const int* __restrict__ ei,
                                                   int* __restrict__ bcur,
                                                   int2* __restrict__ binned) {
    __shared__ int hist[NBUCKET];
    __shared__ int base[NBUCKET];
    int t = threadIdx.x;
    int e0 = blockIdx.x * P1_EPB;
    int e1 = e0 + P1_EPB; if (e1 > N_EDGES) e1 = N_EDGES;
    for (int i = t; i < NBUCKET; i += 256) hist[i] = 0;
    __syncthreads();
    int myrank[P1_EPB / 256];
    int cnt = 0;
    for (int e = e0 + t; e < e1; e += 256) {
        int d = ei[N_EDGES + e];
        myrank[cnt++] = atomicAdd(&hist[d >> BIN_SHIFT], 1);
    }
    __syncthreads();
    for (int i = t; i < NBUCKET; i += 256) base[i] = atomicAdd(&bcur[i], hist[i]);
    __syncthreads();
    cnt = 0;
    for (int e = e0 + t; e < e1; e += 256) {
        int s = ei[e];
        int d = ei[N_EDGES + e];
        binned[base[d >> BIN_SHIFT] + myrank[cnt++]] = make_int2(s, d);
    }
}

// per-bucket: histogram dst -> local scan -> rowoff + dis (replaces global deg+scan)
__global__ __launch_bounds__(256) void k_bucket_build(const int2* __restrict__ binned,
                                                      const int* __restrict__ bucket_off,
                                                      int* __restrict__ rowoff,
                                                      float* __restrict__ dis) {
    __shared__ int cnt[512];
    __shared__ int sa[512];
    __shared__ int sb[512];
    int b = blockIdx.x;
    int t = threadIdx.x;
    int n0 = b << BIN_SHIFT;
    int j0 = bucket_off[b], j1 = bucket_off[b + 1];
    cnt[t] = 0; cnt[t + 256] = 0;
    __syncthreads();
    for (int j = j0 + t; j < j1; j += 256) atomicAdd(&cnt[binned[j].y & 511], 1);
    __syncthreads();
    sa[t] = cnt[t]; sa[t + 256] = cnt[t + 256];
    __syncthreads();
    int* A = sa; int* B = sb;
    for (int off = 1; off < 512; off <<= 1) {
        int i0 = t, i1 = t + 256;
        B[i0] = A[i0] + ((i0 >= off) ? A[i0 - off] : 0);
        B[i1] = A[i1] + ((i1 >= off) ? A[i1 - off] : 0);
        __syncthreads();
        int* tmp = A; A = B; B = tmp;
    }
    // A = inclusive scan
    for (int i = t; i < 512; i += 256) {
        int n = n0 + i;
        if (n < N_NODES) {
            rowoff[n] = j0 + A[i] - cnt[i];
            dis[n] = rsqrtf((float)(1 + cnt[i]));
        }
    }
    if (b == NBUCKET - 1 && t == 0) rowoff[N_NODES] = N_EDGES;
}

// pass 2: one block per bucket; scatter within the bucket's L2-resident window.
__global__ __launch_bounds__(256) void k_scatter(const int2* __restrict__ binned,
                                                 const float* __restrict__ dis,
                                                 const int* __restrict__ rowoff,
                                                 const int* __restrict__ bucket_off,
                                                 int2* __restrict__ csc) {
    __shared__ int lcur[512];
    int b = blockIdx.x;
    int t = threadIdx.x;
    lcur[t] = 0; lcur[t + 256] = 0;
    __syncthreads();
    int j0 = bucket_off[b], j1 = bucket_off[b + 1];
    for (int j = j0 + t; j < j1; j += 256) {
        int2 sd = binned[j];
        float w = dis[sd.x] * dis[sd.y];
        int rank = atomicAdd(&lcur[sd.y & 511], 1);
        csc[rowoff[sd.y] + rank] = make_int2(sd.x, __float_as_int(w));
    }
}

// cast conv_w (fp32, [L][K][N]) -> Wt (bf16, [L][N][K] packed as uint pairs along K)
__global__ void k_cast_w(const float* __restrict__ W, uint32_t* __restrict__ Wt) {
    int i = blockIdx.x * blockDim.x + threadIdx.x;    // over L*128*64
    if (i >= NLAYERS * DIM * 64) return;
    int l = i / (DIM * 64);
    int n = (i / 64) % DIM;
    int ku = i % 64;
    const float* Wl = W + (size_t)l * DIM * DIM;
    float w0 = Wl[(2 * ku) * DIM + n];
    float w1 = Wl[(2 * ku + 1) * DIM + n];
    Wt[i] = pack_bf2(w0, w1);
}

// ---------------- GEMM cores ----------------

// MFMA phase: A-tile in LDS (uint [64][68], bf16 pairs), B = Wt global, out H bf16.
__device__ __forceinline__ void gemm_phase(const uint32_t (*atile)[68], const uint32_t* __restrict__ Wt,
                                           float (*ctile)[132], uint32_t* __restrict__ H,
                                           int blk, int t) {
    int wid = t >> 6;
    int lane = t & 63;
    int quad = lane >> 4;
    int s15 = lane & 15;

    float4_t acc[8];
#pragma unroll
    for (int i = 0; i < 8; i++) acc[i] = (float4_t){0.f, 0.f, 0.f, 0.f};

#pragma unroll
    for (int kk = 0; kk < 4; kk++) {
        uint4 au = *(const uint4*)&atile[wid * 16 + s15][quad * 4 + kk * 16];
        short8_t a = __builtin_bit_cast(short8_t, au);
#pragma unroll
        for (int nt = 0; nt < 8; nt++) {
            uint4 bu = *(const uint4*)(Wt + (size_t)(nt * 16 + s15) * 64 + kk * 16 + quad * 4);
            short8_t b = __builtin_bit_cast(short8_t, bu);
            acc[nt] = __builtin_amdgcn_mfma_f32_16x16x32_bf16(a, b, acc[nt], 0, 0, 0);
        }
    }
    __syncthreads();       // A-tile dead; reuse LDS for C
#pragma unroll
    for (int nt = 0; nt < 8; nt++) {
#pragma unroll
        for (int r = 0; r < 4; r++) {
            ctile[wid * 16 + quad * 4 + r][nt * 16 + s15] = acc[nt][r];
        }
    }
    __syncthreads();
    uint32_t* Hb = H + (size_t)blk * 64 * 64;
#pragma unroll
    for (int i = 0; i < 16; i++) {
        int idx = t + 256 * i;            // over 4096 uints
        int row = idx >> 6, cu = idx & 63;
        float2 v = *(const float2*)&ctile[row][cu * 2];
        Hb[(size_t)row * 64 + cu] = pack_bf2(v.x, v.y);
    }
}

// layer-0 GEMM: cast x_in (fp32) to bf16 A-tile in LDS, then MFMA
__global__ __launch_bounds__(256) void k_gemm0(const float* __restrict__ X, const uint32_t* __restrict__ Wt,
                                               uint32_t* __restrict__ H) {
    __shared__ __align__(16) char smem[64 * 132 * 4];
    uint32_t (*atile)[68] = (uint32_t(*)[68])smem;
    float (*ctile)[132] = (float(*)[132])smem;
    int t = threadIdx.x;
    size_t row0 = (size_t)blockIdx.x * 64;
#pragma unroll
    for (int i = 0; i < 8; i++) {
        int idx = t + 256 * i;            // 2048 float4-groups
        int row = idx >> 5, q = idx & 31;
        size_t gr = row0 + row;
        uint2 p = make_uint2(0u, 0u);
        if (gr < N_NODES) {
            float4 v = ((const float4*)(X + gr * DIM))[q];
            p.x = pack_bf2(v.x, v.y);
            p.y = pack_bf2(v.z, v.w);
        }
        *(uint2*)&atile[row][q * 2] = p;
    }
    __syncthreads();
    gemm_phase(atile, Wt, ctile, H, blockIdx.x, t);
}

// fused GraphNorm+ELU+residual (layer l) + GEMM (layer l+1).
// A = agg in bf16; residual in fp32 (layer 0) or bf16 (layers 1,2); writes bf16 residual out.
template <bool RBF>
__global__ __launch_bounds__(256) void k_norm_gemm(const uint32_t* __restrict__ A, const int* __restrict__ batch,
                                                   const float* __restrict__ amean, const float* __restrict__ rstd,
                                                   const float* __restrict__ gw, const float* __restrict__ gb,
                                                   const void* __restrict__ res, uint32_t* __restrict__ res_out,
                                                   const uint32_t* __restrict__ Wt, uint32_t* __restrict__ H) {
    __shared__ __align__(16) char smem[64 * 132 * 4];
    uint32_t (*atile)[68] = (uint32_t(*)[68])smem;
    float (*ctile)[132] = (float(*)[132])smem;
    int t = threadIdx.x;
    size_t row0 = (size_t)blockIdx.x * 64;
#pragma unroll
    for (int i = 0; i < 8; i++) {
        int idx = t + 256 * i;            // 2048 float4-groups
        int row = idx >> 5, q = idx & 31;
        size_t gr = row0 + row;
        uint2 p = make_uint2(0u, 0u);
        if (gr < N_NODES) {
            int g = batch[gr];
            float4 v = unpack4(((const uint2*)(A + gr * 64))[q]);
            float4 am = ((const float4*)amean)[g * 32 + q];
            float4 rs = ((const float4*)rstd)[g * 32 + q];
            float4 w = ((const float4*)gw)[q];
            float4 b = ((const float4*)gb)[q];
            float4 r;
            if (RBF) r = unpack4(((const uint2*)((const uint32_t*)res + gr * 64))[q]);
            else     r = ((const float4*)res)[gr * 32 + q];
            float4 o;
            o.x = w.x * (v.x - am.x) * rs.x + b.x;
            o.y = w.y * (v.y - am.y) * rs.y + b.y;
            o.z = w.z * (v.z - am.z) * rs.z + b.z;
            o.w = w.w * (v.w - am.w) * rs.w + b.w;
            o.x = ((o.x > 0.f) ? o.x : expm1f(o.x)) + r.x;
            o.y = ((o.y > 0.f) ? o.y : expm1f(o.y)) + r.y;
            o.z = ((o.z > 0.f) ? o.z : expm1f(o.z)) + r.z;
            o.w = ((o.w > 0.f) ? o.w : expm1f(o.w)) + r.w;
            p.x = pack_bf2(o.x, o.y);
            p.y = pack_bf2(o.z, o.w);
            ((uint2*)(res_out + gr * 64))[q] = p;
        }
        *(uint2*)&atile[row][q * 2] = p;
    }
    __syncthreads();
    gemm_phase(atile, Wt, ctile, H, blockIdx.x, t);
}

// ---------------- per-layer kernels ----------------

// pull aggregation: 1 wave per node, quarter-wave rows; 4-deep gather pipeline.
// Each quarter-wave handles 4 CONSECUTIVE edges per iteration -> 16 edges/iter/wave,
// 4 independent 256B row-gathers in flight per quarter (latency hiding for L3 hits).
__global__ __launch_bounds__(256) void k_aggregate(const uint32_t* __restrict__ H,
                                                   const int2* __restrict__ csc,
                                                   const int* __restrict__ rowoff,
                                                   const float* __restrict__ dis,
                                                   const float* __restrict__ bias,
                                                   uint32_t* __restrict__ Out) {
    int wid = threadIdx.x >> 6;
    int lane = threadIdx.x & 63;
    int q = lane >> 4;
    int s = lane & 15;
    int n = blockIdx.x * 4 + wid;     // grid = N/4 exactly

    float acc[8];
    {
        float d = dis[n];
        float sw = (q == 0) ? d * d : 0.f;     // self term counted once (quad 0)
        uint4 us = ((const uint4*)(H + (size_t)n * 64))[s];
        acc[0] = sw * bf_lo(us.x); acc[1] = sw * bf_hi(us.x);
        acc[2] = sw * bf_lo(us.y); acc[3] = sw * bf_hi(us.y);
        acc[4] = sw * bf_lo(us.z); acc[5] = sw * bf_hi(us.z);
        acc[6] = sw * bf_lo(us.w); acc[7] = sw * bf_hi(us.w);
    }

    int b0 = rowoff[n], b1 = rowoff[n + 1];
    for (int j = b0; j < b1; j += 16) {
        int base = j + 4 * q;         // quarter q owns edges [base, base+4)
        int e0 = base, e1 = base + 1, e2 = base + 2, e3 = base + 3;
        int2 c0 = csc[(e0 < b1) ? e0 : b0];
        int2 c1 = csc[(e1 < b1) ? e1 : b0];
        int2 c2 = csc[(e2 < b1) ? e2 : b0];
        int2 c3 = csc[(e3 < b1) ? e3 : b0];
        float w0 = (e0 < b1) ? __int_as_float(c0.y) : 0.f;
        float w1 = (e1 < b1) ? __int_as_float(c1.y) : 0.f;
        float w2 = (e2 < b1) ? __int_as_float(c2.y) : 0.f;
        float w3 = (e3 < b1) ? __int_as_float(c3.y) : 0.f;
        uint4 u0 = ((const uint4*)(H + (size_t)c0.x * 64))[s];
        uint4 u1 = ((const uint4*)(H + (size_t)c1.x * 64))[s];
        uint4 u2 = ((const uint4*)(H + (size_t)c2.x * 64))[s];
        uint4 u3 = ((const uint4*)(H + (size_t)c3.x * 64))[s];
        acc[0] += w0 * bf_lo(u0.x); acc[1] += w0 * bf_hi(u0.x);
        acc[2] += w0 * bf_lo(u0.y); acc[3] += w0 * bf_hi(u0.y);
        acc[4] += w0 * bf_lo(u0.z); acc[5] += w0 * bf_hi(u0.z);
        acc[6] += w0 * bf_lo(u0.w); acc[7] += w0 * bf_hi(u0.w);
        acc[0] += w1 * bf_lo(u1.x); acc[1] += w1 * bf_hi(u1.x);
        acc[2] += w1 * bf_lo(u1.y); acc[3] += w1 * bf_hi(u1.y);
        acc[4] += w1 * bf_lo(u1.z); acc[5] += w1 * bf_hi(u1.z);
        acc[6] += w1 * bf_lo(u1.w); acc[7] += w1 * bf_hi(u1.w);
        acc[0] += w2 * bf_lo(u2.x); acc[1] += w2 * bf_hi(u2.x);
        acc[2] += w2 * bf_lo(u2.y); acc[3] += w2 * bf_hi(u2.y);
        acc[4] += w2 * bf_lo(u2.z); acc[5] += w2 * bf_hi(u2.z);
        acc[6] += w2 * bf_lo(u2.w); acc[7] += w2 * bf_hi(u2.w);
        acc[0] += w3 * bf_lo(u3.x); acc[1] += w3 * bf_hi(u3.x);
        acc[2] += w3 * bf_lo(u3.y); acc[3] += w3 * bf_hi(u3.y);
        acc[4] += w3 * bf_lo(u3.z); acc[5] += w3 * bf_hi(u3.z);
        acc[6] += w3 * bf_lo(u3.w); acc[7] += w3 * bf_hi(u3.w);
    }
    // combine quarters
#pragma unroll
    for (int k = 0; k < 8; k++) {
        acc[k] += __shfl_xor(acc[k], 16);
        acc[k] += __shfl_xor(acc[k], 32);
    }
    // lane (q,s) owns feature pair index s*4+q (feats s*8+2q, s*8+2q+1) -> coalesced 256B
    float o0 = (q == 0) ? acc[0] : (q == 1) ? acc[2] : (q == 2) ? acc[4] : acc[6];
    float o1 = (q == 0) ? acc[1] : (q == 1) ? acc[3] : (q == 2) ? acc[5] : acc[7];
    float2 bb = ((const float2*)bias)[s * 4 + q];
    Out[(size_t)n * 64 + s * 4 + q] = pack_bf2(o0 + bb.x, o1 + bb.y);
}

// GraphNorm stats from bf16 agg: one block per graph, 512 thr (8 parts x 64 uints)
__global__ __launch_bounds__(512) void k_stats(const uint32_t* __restrict__ A, const int* __restrict__ gstart,
                                               const float* __restrict__ mscale,
                                               float* __restrict__ amean, float* __restrict__ rstd) {
    __shared__ float L1[8][DIM];
    __shared__ float L2[8][DIM];
    int g = blockIdx.x;
    int t = threadIdx.x;
    int f2 = t & 63;
    int p = t >> 6;
    int s0 = gstart[g], s1 = gstart[g + 1];
    float sa = 0.f, sb = 0.f, qa = 0.f, qb = 0.f;
    for (int n = s0 + p; n < s1; n += 8) {
        uint32_t u = A[(size_t)n * 64 + f2];
        float a = bf_lo(u), b = bf_hi(u);
        sa += a; qa += a * a;
        sb += b; qb += b * b;
    }
    L1[p][2 * f2] = sa; L1[p][2 * f2 + 1] = sb;
    L2[p][2 * f2] = qa; L2[p][2 * f2 + 1] = qb;
    __syncthreads();
    if (t < DIM) {
        float s = 0.f, s2 = 0.f;
#pragma unroll
        for (int i = 0; i < 8; i++) { s += L1[i][t]; s2 += L2[i][t]; }
        int cnt = s1 - s0;
        float inv = (cnt > 0) ? 1.0f / (float)cnt : 0.f;
        float m = s * inv;
        float a = mscale[t];
        float var = s2 * inv - (2.f * a - a * a) * m * m;
        amean[g * DIM + t] = a * m;
        rstd[g * DIM + t] = rsqrtf(var + EPSV);
    }
}

// fused final-layer norm+ELU+residual + x write + global_add_pool + dense head
__global__ __launch_bounds__(512) void k_pool_head(const uint32_t* __restrict__ A,
                                                   const uint32_t* __restrict__ resb,
                                                   const int* __restrict__ gstart,
                                                   const float* __restrict__ amean, const float* __restrict__ rstd,
                                                   const float* __restrict__ gw, const float* __restrict__ gb,
                                                   const float* __restrict__ w1, const float* __restrict__ b1,
                                                   const float* __restrict__ gamma, const float* __restrict__ beta,
                                                   const float* __restrict__ rmean, const float* __restrict__ rvar,
                                                   const float* __restrict__ w2, const float* __restrict__ b2,
                                                   float* __restrict__ outx, float* __restrict__ zout) {
    __shared__ float L[8][DIM];
    __shared__ float sp[DIM];
    __shared__ float sz[DIM];
    int g = blockIdx.x, t = threadIdx.x;
    int f2 = t & 63;
    int p = t >> 6;
    int s0 = gstart[g], s1 = gstart[g + 1];
    float am0 = amean[g * DIM + 2 * f2], am1 = amean[g * DIM + 2 * f2 + 1];
    float rs0 = rstd[g * DIM + 2 * f2],  rs1 = rstd[g * DIM + 2 * f2 + 1];
    float w0_ = gw[2 * f2], w1_ = gw[2 * f2 + 1];
    float b0_ = gb[2 * f2], b1_ = gb[2 * f2 + 1];
    float p0 = 0.f, p1 = 0.f;
    for (int n = s0 + p; n < s1; n += 8) {
        uint32_t u = A[(size_t)n * 64 + f2];
        uint32_t ur = resb[(size_t)n * 64 + f2];
        float a = bf_lo(u), b = bf_hi(u);
        float r0 = bf_lo(ur), r1 = bf_hi(ur);
        float o0 = w0_ * (a - am0) * rs0 + b0_;
        float o1 = w1_ * (b - am1) * rs1 + b1_;
        o0 = ((o0 > 0.f) ? o0 : expm1f(o0)) + r0;
        o1 = ((o1 > 0.f) ? o1 : expm1f(o1)) + r1;
        ((float2*)(outx + (size_t)n * DIM))[f2] = make_float2(o0, o1);
        p0 += o0; p1 += o1;
    }
    L[p][2 * f2] = p0; L[p][2 * f2 + 1] = p1;
    __syncthreads();
    if (t < DIM) {
        float s = 0.f;
#pragma unroll
        for (int i = 0; i < 8; i++) s += L[i][t];
        sp[t] = s;
    }
    __syncthreads();
    if (t < DIM) {
        float acc = b1[t];
#pragma unroll 8
        for (int k = 0; k < DIM; k++) acc += sp[k] * w1[k * DIM + t];
        acc = gamma[t] * (acc - rmean[t]) * rsqrtf(rvar[t] + EPSV) + beta[t];
        sz[t] = fmaxf(acc, 0.f);
    }
    __syncthreads();
    if (t < NCLS) {
        float a2 = b2[t];
#pragma unroll 8
        for (int k = 0; k < DIM; k++) a2 += sz[k] * w2[k * NCLS + t];
        zout[g * NCLS + t] = a2;
    }
}

// ---------------- launch ----------------

extern "C" void kernel_launch(void* const* d_in, const int* in_sizes, int n_in,
                              void* d_out, int out_size, void* d_ws, size_t ws_size,
                              hipStream_t stream) {
    const float* x_in   = (const float*)d_in[0];
    const int*   ei     = (const int*)d_in[1];
    const int*   batch  = (const int*)d_in[2];
    const float* conv_w = (const float*)d_in[3];
    const float* conv_b = (const float*)d_in[4];
    const float* gn_w   = (const float*)d_in[5];
    const float* gn_b   = (const float*)d_in[6];
    const float* gn_ms  = (const float*)d_in[7];
    const float* w1     = (const float*)d_in[8];
    const float* b1     = (const float*)d_in[9];
    const float* bng    = (const float*)d_in[10];
    const float* bnb    = (const float*)d_in[11];
    const float* bnm    = (const float*)d_in[12];
    const float* bnv    = (const float*)d_in[13];
    const float* w2     = (const float*)d_in[14];
    const float* b2     = (const float*)d_in[15];

    float* out_x = (float*)d_out;
    float* out_z = out_x + (size_t)N_NODES * DIM;

    char* ws = (char*)d_ws;
    size_t off = 0;
    auto alloc = [&](size_t bytes) -> void* {
        void* p = ws + off;
        off += (bytes + 255) / 256 * 256;
        return p;
    };
    uint32_t* h      = (uint32_t*)alloc(sizeof(uint32_t) * (size_t)N_PAD * 64);   // bf16 H (padded)
    uint32_t* agg    = (uint32_t*)alloc(sizeof(uint32_t) * (size_t)N_NODES * 64); // bf16 agg
    uint32_t* resb   = (uint32_t*)alloc(sizeof(uint32_t) * (size_t)N_NODES * 64); // bf16 residual stream
    int2*  csc       = (int2*)alloc(sizeof(int2) * (size_t)N_EDGES);              // merged (src, w)
    int2*  binned    = (int2*)alloc(sizeof(int2) * (size_t)N_EDGES);              // pass-1 bins (src, dst)
    uint32_t* wt     = (uint32_t*)alloc(sizeof(uint32_t) * NLAYERS * DIM * 64);   // bf16 W^T
    float* dis       = (float*)alloc(sizeof(float) * N_NODES);
    int*   rowoff    = (int*)alloc(sizeof(int) * (N_NODES + 1));
    int*   bcnt      = (int*)alloc(sizeof(int) * NBUCKET);
    int*   boffb     = (int*)alloc(sizeof(int) * (NBUCKET + 1));
    int*   bcur      = (int*)alloc(sizeof(int) * NBUCKET);
    int*   gstart    = (int*)alloc(sizeof(int) * (NGRAPH + 1));
    float* amean     = (float*)alloc(sizeof(float) * NGRAPH * DIM);
    float* rstd      = (float*)alloc(sizeof(float) * NGRAPH * DIM);

    // ---- prepass ----
    k_node_meta<<<(N_NODES + 255) / 256, 256, 0, stream>>>(batch, gstart, bcnt);
    k_bhist<<<P1_BLOCKS, 256, 0, stream>>>(ei, bcnt);
    k_bscan<<<1, 256, 0, stream>>>(bcnt, boffb, bcur);
    k_bin_edges<<<P1_BLOCKS, 256, 0, stream>>>(ei, bcur, binned);
    k_bucket_build<<<NBUCKET, 256, 0, stream>>>(binned, boffb, rowoff, dis);
    k_scatter<<<NBUCKET, 256, 0, stream>>>(binned, dis, rowoff, boffb, csc);
    k_cast_w<<<(NLAYERS * DIM * 64 + 255) / 256, 256, 0, stream>>>(conv_w, wt);

    // ---- layers ----
    k_gemm0<<<N_PAD / 64, 256, 0, stream>>>(x_in, wt, h);
    for (int l = 0; l < NLAYERS; l++) {
        k_aggregate<<<N_NODES / 4, 256, 0, stream>>>(h, csc, rowoff, dis, conv_b + (size_t)l * DIM, agg);
        k_stats<<<NGRAPH, 512, 0, stream>>>(agg, gstart, gn_ms + (size_t)l * DIM, amean, rstd);
        if (l == 0) {
            k_norm_gemm<false><<<N_PAD / 64, 256, 0, stream>>>(agg, batch, amean, rstd, gn_w, gn_b,
                                                               (const void*)x_in, resb,
                                                               wt + (size_t)1 * DIM * 64, h);
        } else if (l < NLAYERS - 1) {
            k_norm_gemm<true><<<N_PAD / 64, 256, 0, stream>>>(agg, batch, amean, rstd,
                                                              gn_w + (size_t)l * DIM, gn_b + (size_t)l * DIM,
                                                              (const void*)resb, resb,
                                                              wt + (size_t)(l + 1) * DIM * 64, h);
        } else {
            k_pool_head<<<NGRAPH, 512, 0, stream>>>(agg, resb, gstart, amean, rstd,
                                                    gn_w + (size_t)l * DIM, gn_b + (size_t)l * DIM,
                                                    w1, b1, bng, bnb, bnm, bnv, w2, b2, out_x, out_z);
        }
    }
}